// Round 3
// baseline (159.633 us; speedup 1.0000x reference)
//
#include <hip/hip_runtime.h>

#define NTOT 4096
#define FD 32
#define BATCH 4

typedef __attribute__((ext_vector_type(8))) _Float16 half8;
typedef __attribute__((ext_vector_type(4))) _Float16 half4;
typedef __attribute__((ext_vector_type(2))) _Float16 half2v;
typedef __attribute__((ext_vector_type(4))) float f32x4;

__device__ __forceinline__ float tanh_pos(float t) {
    // tanh(t) for t >= 0:  1 - 2/(1+e^{2t});  t=inf -> 1 correctly
    float u = __builtin_amdgcn_exp2f(t * 2.885390081777927f); // e^{2t}
    float r = __builtin_amdgcn_rcpf(u + 1.0f);
    return __builtin_fmaf(-2.0f, r, 1.0f);
}

__device__ __forceinline__ float eluf(float x) {
    return x > 0.0f ? x : (__builtin_amdgcn_exp2f(x * 1.4426950408889634f) - 1.0f);
}

// Convert X (f32, [B][NT][F]) -> Xh (f16 row-major) and Xht (f16 transposed [B][F][NT])
__global__ __launch_bounds__(256) void convert_x(const float* __restrict__ X,
                                                 _Float16* __restrict__ Xh,
                                                 _Float16* __restrict__ Xht) {
    __shared__ float lds[FD * 129];
    const int tid = threadIdx.x;
    const int b = blockIdx.x >> 5;          // 32 blocks per batch
    const int nbase = (blockIdx.x & 31) << 7;  // 128 rows per block
    const float* Xp = X + ((size_t)b * NTOT + nbase) * FD;
    _Float16* Xhp = Xh + ((size_t)b * NTOT + nbase) * FD;
#pragma unroll
    for (int k = 0; k < 16; ++k) {
        int e = tid + k * 256;
        int n = e >> 5, f = e & 31;
        float x = Xp[e];
        Xhp[e] = (_Float16)x;
        lds[f * 129 + n] = x;
    }
    __syncthreads();
    _Float16* Xtp = Xht + (size_t)b * FD * NTOT + nbase;
#pragma unroll
    for (int k = 0; k < 16; ++k) {
        int o = tid + k * 256;
        int f = o >> 7, nl = o & 127;
        Xtp[(size_t)f * NTOT + nl] = (_Float16)lds[f * 129 + nl];
    }
}

// One GCN layer:  out = elu( adj @ V @ W ),  adj = tanh(relu(X X^T) + I)
// 16 rows per block, 8 waves each owning a 512-col strip (32 iters of 16 cols).
// LAYER==0: write outHt (f16 [B][FD][NT]); LAYER==1: write outF (f32 [B][NT][FD])
template <int LAYER>
__global__ __launch_bounds__(512, 8) void gcn_layer_kernel(const _Float16* __restrict__ Xh,
                                                           const _Float16* __restrict__ Vt,
                                                           const float* __restrict__ Wg,
                                                           _Float16* __restrict__ outHt,
                                                           float* __restrict__ outF) {
    __shared__ float lds_part[8 * 32 * 16];  // per-wave partial O^T [wv][f][r], 16 KB

    const int tid = threadIdx.x;
    const int lane = tid & 63;
    const int wv = tid >> 6;                      // 8 waves
    const int b = blockIdx.x >> 8;                // 256 row-blocks per batch
    const int rowbase = (blockIdx.x & 255) << 4;  // 16 rows per block
    const int l15 = lane & 15;
    const int lg = lane >> 4;  // 0..3

    const _Float16* Xb = Xh + (size_t)b * NTOT * FD;
    // Q fragment (B-operand of 16x16x32: lane holds Q[l15][lg*8 + 0..7])
    const half8 q1 = *(const half8*)(Xb + (size_t)(rowbase + l15) * FD + lg * 8);

    const int col0 = wv << 9;  // each wave owns 512 columns
    const _Float16* kp = Xb + (size_t)(col0 + l15) * FD + lg * 8;
    const _Float16* Vb = Vt + (size_t)b * FD * NTOT;
    const _Float16* vp0 = Vb + (size_t)l15 * NTOT + col0 + lg * 4;
    const _Float16* vp1 = vp0 + 16 * NTOT;

    f32x4 acc0 = {0.f, 0.f, 0.f, 0.f}, acc1 = {0.f, 0.f, 0.f, 0.f};
    const f32x4 zero = {0.f, 0.f, 0.f, 0.f};

    // iteration whose 16-col tile contains the diagonal (may be out of [0,32))
    const int diag_it = (rowbase - col0) >> 4;

    // 1-deep software prefetch: load iter 0 now; inside the loop issue iter i+1's
    // loads before computing iter i, so L2 latency hides under MFMA+tanh.
    half8 kf = *(const half8*)kp;
    half4 v0 = *(const half4*)vp0;
    half4 v1 = *(const half4*)vp1;

    for (int it = 0; it < 32; ++it) {
        half8 kc = kf;
        half4 vc0 = v0, vc1 = v1;
        if (it < 31) {  // wave-uniform branch
            kp += 16 * FD; vp0 += 16; vp1 += 16;
            kf = *(const half8*)kp;
            v0 = *(const half4*)vp0;
            v1 = *(const half4*)vp1;
        }

        // S^T tile: D[m][r], m = col = lg*4+e, r = row = l15
        f32x4 s = __builtin_amdgcn_mfma_f32_16x16x32_f16(kc, q1, zero, 0, 0, 0);

        float t[4];
#pragma unroll
        for (int e = 0; e < 4; ++e) t[e] = fmaxf(s[e], 0.0f);
        if (it == diag_it) {
#pragma unroll
            for (int e = 0; e < 4; ++e)
                if (lg * 4 + e == l15) t[e] += 1.0f;
        }
#pragma unroll
        for (int e = 0; e < 4; ++e) t[e] = tanh_pos(t[e]);

        half2v a0 = __builtin_bit_cast(half2v, __builtin_amdgcn_cvt_pkrtz(t[0], t[1]));
        half2v a1 = __builtin_bit_cast(half2v, __builtin_amdgcn_cvt_pkrtz(t[2], t[3]));
        half4 p = __builtin_shufflevector(a0, a1, 0, 1, 2, 3);

        // O^T += V^T * P^T  (S^T output layout == B-operand layout of 16x16x16)
        acc0 = __builtin_amdgcn_mfma_f32_16x16x16f16(vc0, p, acc0, 0, 0, 0);
        acc1 = __builtin_amdgcn_mfma_f32_16x16x16f16(vc1, p, acc1, 0, 0, 0);
    }

    // ---- store per-wave partial O^T [f=32][r=16] ----
#pragma unroll
    for (int e = 0; e < 4; ++e) {
        int f0 = lg * 4 + e;
        lds_part[(wv * 32 + f0) * 16 + l15] = acc0[e];
        lds_part[(wv * 32 + 16 + f0) * 16 + l15] = acc1[e];
    }
    __syncthreads();

    // ---- reduce 8 wave partials: thread owns flat (f,r) = tid ----
    {
        float ssum = 0.0f;
#pragma unroll
        for (int ww = 0; ww < 8; ++ww) ssum += lds_part[ww * 512 + tid];
        lds_part[tid] = ssum;  // slot tid only ever read/written by thread tid here
    }
    __syncthreads();

    // ---- G = O @ W, elu, write (per-layer mapping for contiguous stores) ----
    int r, g;
    if (LAYER == 0) { r = tid & 15; g = tid >> 4; }
    else            { g = tid & 31; r = tid >> 5; }
    float a = 0.0f;
#pragma unroll
    for (int f = 0; f < FD; ++f)
        a = __builtin_fmaf(lds_part[f * 16 + r], Wg[f * FD + g], a);
    a = eluf(a);

    if (LAYER == 0) {
        outHt[(size_t)b * FD * NTOT + (size_t)g * NTOT + rowbase + r] = (_Float16)a;
    } else {
        outF[((size_t)b * NTOT + rowbase + r) * FD + g] = a;
    }
}

extern "C" void kernel_launch(void* const* d_in, const int* in_sizes, int n_in,
                              void* d_out, int out_size, void* d_ws, size_t ws_size,
                              hipStream_t stream) {
    const float* X = (const float*)d_in[0];  // [B][NT][FD] f32
    const float* W = (const float*)d_in[1];  // [2][FD][FD] f32
    float* out = (float*)d_out;              // [B][NT][FD] f32

    _Float16* Xh = (_Float16*)d_ws;                  // 1 MB
    _Float16* Xht = Xh + (size_t)BATCH * NTOT * FD;  // 1 MB
    _Float16* H1t = Xht + (size_t)BATCH * NTOT * FD; // 1 MB

    convert_x<<<128, 256, 0, stream>>>(X, Xh, Xht);
    gcn_layer_kernel<0><<<BATCH * 256, 512, 0, stream>>>(Xh, Xht, W, H1t, nullptr);
    gcn_layer_kernel<1><<<BATCH * 256, 512, 0, stream>>>(Xh, H1t, W + FD * FD, nullptr, out);
}

// Round 4
// 89.137 us; speedup vs baseline: 1.7909x; 1.7909x over previous
//
#include <hip/hip_runtime.h>

#define NTOT 4096
#define FD 32
#define BATCH 4

typedef __attribute__((ext_vector_type(8))) _Float16 half8;
typedef __attribute__((ext_vector_type(4))) _Float16 half4;
typedef __attribute__((ext_vector_type(2))) _Float16 half2v;
typedef __attribute__((ext_vector_type(4))) float f32x4;

__device__ __forceinline__ float tanh_pos(float t) {
    // tanh(t) for t >= 0:  1 - 2/(1+e^{2t});  t=inf -> 1 correctly
    float u = __builtin_amdgcn_exp2f(t * 2.885390081777927f); // e^{2t}
    float r = __builtin_amdgcn_rcpf(u + 1.0f);
    return __builtin_fmaf(-2.0f, r, 1.0f);
}

__device__ __forceinline__ float eluf(float x) {
    return x > 0.0f ? x : (__builtin_amdgcn_exp2f(x * 1.4426950408889634f) - 1.0f);
}

// Convert X (f32, [B][NT][F]) -> Xh (f16 row-major) and Xht (f16 transposed [B][F][NT])
__global__ __launch_bounds__(256) void convert_x(const float* __restrict__ X,
                                                 _Float16* __restrict__ Xh,
                                                 _Float16* __restrict__ Xht) {
    __shared__ float lds[FD * 129];
    const int tid = threadIdx.x;
    const int b = blockIdx.x >> 5;          // 32 blocks per batch
    const int nbase = (blockIdx.x & 31) << 7;  // 128 rows per block
    const float* Xp = X + ((size_t)b * NTOT + nbase) * FD;
    _Float16* Xhp = Xh + ((size_t)b * NTOT + nbase) * FD;
#pragma unroll
    for (int k = 0; k < 16; ++k) {
        int e = tid + k * 256;
        int n = e >> 5, f = e & 31;
        float x = Xp[e];
        Xhp[e] = (_Float16)x;
        lds[f * 129 + n] = x;
    }
    __syncthreads();
    _Float16* Xtp = Xht + (size_t)b * FD * NTOT + nbase;
#pragma unroll
    for (int k = 0; k < 16; ++k) {
        int o = tid + k * 256;
        int f = o >> 7, nl = o & 127;
        Xtp[(size_t)f * NTOT + nl] = (_Float16)lds[f * 129 + nl];
    }
}

// One GCN layer:  out = elu( adj @ V @ W ),  adj = tanh(relu(X X^T) + I)
// 32 rows per block, 8 waves each owning a 512-col strip, 16 iters of 32 cols.
// Per iter: 4 QK MFMA + 16 tanh + 8 PV MFMA (4 independent chains), 6 loads.
// LAYER==0: write outHt (f16 [B][FD][NT]); LAYER==1: write outF (f32 [B][NT][FD])
template <int LAYER>
__global__ __launch_bounds__(512, 4) void gcn_layer_kernel(const _Float16* __restrict__ Xh,
                                                           const _Float16* __restrict__ Vt,
                                                           const float* __restrict__ Wg,
                                                           _Float16* __restrict__ outHt,
                                                           float* __restrict__ outF) {
    __shared__ float lds_part[8 * 32 * 32];  // per-wave partial O^T [wv][f][r], 32 KB

    const int tid = threadIdx.x;
    const int lane = tid & 63;
    const int wv = tid >> 6;                      // 8 waves
    const int b = blockIdx.x >> 7;                // 128 row-blocks per batch
    const int rowbase = (blockIdx.x & 127) << 5;  // 32 rows per block
    const int l15 = lane & 15;
    const int lg = lane >> 4;  // 0..3

    const _Float16* Xb = Xh + (size_t)b * NTOT * FD;
    // Q fragments (B-operand of 16x16x32: lane holds Q[l15][lg*8 + 0..7])
    const half8 q1 = *(const half8*)(Xb + (size_t)(rowbase + l15) * FD + lg * 8);
    const half8 q2 = *(const half8*)(Xb + (size_t)(rowbase + 16 + l15) * FD + lg * 8);

    const int col0 = wv << 9;  // each wave owns 512 columns
    const _Float16* kp = Xb + (size_t)(col0 + l15) * FD + lg * 8;
    const _Float16* Vb = Vt + (size_t)b * FD * NTOT;
    const _Float16* vpLo = Vb + (size_t)l15 * NTOT + col0 + lg * 4;         // f 0..15
    const _Float16* vpHi = vpLo + (size_t)16 * NTOT;                        // f 16..31

    // acc[f-half][r-half] of the 32x32 O^T tile
    f32x4 accA0 = {0.f, 0.f, 0.f, 0.f}, accA1 = {0.f, 0.f, 0.f, 0.f};
    f32x4 accB0 = {0.f, 0.f, 0.f, 0.f}, accB1 = {0.f, 0.f, 0.f, 0.f};
    const f32x4 zero = {0.f, 0.f, 0.f, 0.f};

    // 1-deep software prefetch with all-distinct registers
    half8 k0n = *(const half8*)kp;
    half8 k1n = *(const half8*)(kp + 16 * FD);
    half4 v00n = *(const half4*)vpLo;
    half4 v10n = *(const half4*)(vpLo + 16);
    half4 v01n = *(const half4*)vpHi;
    half4 v11n = *(const half4*)(vpHi + 16);

    for (int it = 0; it < 16; ++it) {
        const int colbase = col0 + (it << 5);
        half8 k0 = k0n, k1 = k1n;
        half4 v00 = v00n, v01 = v01n, v10 = v10n, v11 = v11n;
        if (it < 15) {  // wave-uniform
            kp += 32 * FD; vpLo += 32; vpHi += 32;
            k0n = *(const half8*)kp;
            k1n = *(const half8*)(kp + 16 * FD);
            v00n = *(const half4*)vpLo;
            v10n = *(const half4*)(vpLo + 16);
            v01n = *(const half4*)vpHi;
            v11n = *(const half4*)(vpHi + 16);
        }

        // S^T tiles: D[c][r], c = lg*4+e (col within 16-chunk), r = l15 (Q row)
        f32x4 s00 = __builtin_amdgcn_mfma_f32_16x16x32_f16(k0, q1, zero, 0, 0, 0);
        f32x4 s01 = __builtin_amdgcn_mfma_f32_16x16x32_f16(k0, q2, zero, 0, 0, 0);
        f32x4 s10 = __builtin_amdgcn_mfma_f32_16x16x32_f16(k1, q1, zero, 0, 0, 0);
        f32x4 s11 = __builtin_amdgcn_mfma_f32_16x16x32_f16(k1, q2, zero, 0, 0, 0);

        float t00[4], t01[4], t10[4], t11[4];
#pragma unroll
        for (int e = 0; e < 4; ++e) {
            t00[e] = fmaxf(s00[e], 0.0f);
            t01[e] = fmaxf(s01[e], 0.0f);
            t10[e] = fmaxf(s10[e], 0.0f);
            t11[e] = fmaxf(s11[e], 0.0f);
        }
        // diagonal: 32-aligned row-range == 32-aligned col-range only when equal;
        // then diag lives in (chunk0 x q1) and (chunk1 x q2) at c==r.
        if (colbase == rowbase) {
#pragma unroll
            for (int e = 0; e < 4; ++e)
                if (lg * 4 + e == l15) { t00[e] += 1.0f; t11[e] += 1.0f; }
        }
#pragma unroll
        for (int e = 0; e < 4; ++e) {
            t00[e] = tanh_pos(t00[e]);
            t01[e] = tanh_pos(t01[e]);
            t10[e] = tanh_pos(t10[e]);
            t11[e] = tanh_pos(t11[e]);
        }

        half4 p00 = __builtin_shufflevector(
            __builtin_bit_cast(half2v, __builtin_amdgcn_cvt_pkrtz(t00[0], t00[1])),
            __builtin_bit_cast(half2v, __builtin_amdgcn_cvt_pkrtz(t00[2], t00[3])), 0, 1, 2, 3);
        half4 p01 = __builtin_shufflevector(
            __builtin_bit_cast(half2v, __builtin_amdgcn_cvt_pkrtz(t01[0], t01[1])),
            __builtin_bit_cast(half2v, __builtin_amdgcn_cvt_pkrtz(t01[2], t01[3])), 0, 1, 2, 3);
        half4 p10 = __builtin_shufflevector(
            __builtin_bit_cast(half2v, __builtin_amdgcn_cvt_pkrtz(t10[0], t10[1])),
            __builtin_bit_cast(half2v, __builtin_amdgcn_cvt_pkrtz(t10[2], t10[3])), 0, 1, 2, 3);
        half4 p11 = __builtin_shufflevector(
            __builtin_bit_cast(half2v, __builtin_amdgcn_cvt_pkrtz(t11[0], t11[1])),
            __builtin_bit_cast(half2v, __builtin_amdgcn_cvt_pkrtz(t11[2], t11[3])), 0, 1, 2, 3);

        // O^T += V^T * P^T  (S^T output layout == B-operand layout of 16x16x16)
        accA0 = __builtin_amdgcn_mfma_f32_16x16x16f16(v00, p00, accA0, 0, 0, 0);
        accA1 = __builtin_amdgcn_mfma_f32_16x16x16f16(v00, p01, accA1, 0, 0, 0);
        accB0 = __builtin_amdgcn_mfma_f32_16x16x16f16(v01, p00, accB0, 0, 0, 0);
        accB1 = __builtin_amdgcn_mfma_f32_16x16x16f16(v01, p01, accB1, 0, 0, 0);
        accA0 = __builtin_amdgcn_mfma_f32_16x16x16f16(v10, p10, accA0, 0, 0, 0);
        accA1 = __builtin_amdgcn_mfma_f32_16x16x16f16(v10, p11, accA1, 0, 0, 0);
        accB0 = __builtin_amdgcn_mfma_f32_16x16x16f16(v11, p10, accB0, 0, 0, 0);
        accB1 = __builtin_amdgcn_mfma_f32_16x16x16f16(v11, p11, accB1, 0, 0, 0);
    }

    // ---- store per-wave partial O^T [f=32][r=32] ----
#pragma unroll
    for (int e = 0; e < 4; ++e) {
        int f0 = lg * 4 + e;
        lds_part[(wv * 32 + f0) * 32 + l15] = accA0[e];
        lds_part[(wv * 32 + f0) * 32 + 16 + l15] = accA1[e];
        lds_part[(wv * 32 + 16 + f0) * 32 + l15] = accB0[e];
        lds_part[(wv * 32 + 16 + f0) * 32 + 16 + l15] = accB1[e];
    }
    __syncthreads();

    // ---- reduce 8 wave partials over 1024 (f,r) slots, 2 per thread ----
#pragma unroll
    for (int k = 0; k < 2; ++k) {
        int o = tid + k * 512;
        float ssum = 0.0f;
#pragma unroll
        for (int ww = 0; ww < 8; ++ww) ssum += lds_part[ww * 1024 + o];
        lds_part[o] = ssum;  // slot o only touched by its owner between barriers
    }
    __syncthreads();

    // ---- G = O @ W, elu, write (per-layer mapping for contiguous stores) ----
    if (LAYER == 0) {
        const int r = tid & 31, gg = tid >> 5;  // gg 0..15 -> g = gg, gg+16
        float a0 = 0.0f, a1 = 0.0f;
#pragma unroll
        for (int f = 0; f < FD; ++f) {
            float val = lds_part[f * 32 + r];
            a0 = __builtin_fmaf(val, Wg[f * FD + gg], a0);
            a1 = __builtin_fmaf(val, Wg[f * FD + gg + 16], a1);
        }
        a0 = eluf(a0);
        a1 = eluf(a1);
        _Float16* dst = outHt + (size_t)b * FD * NTOT + rowbase + r;
        dst[(size_t)gg * NTOT] = (_Float16)a0;
        dst[(size_t)(gg + 16) * NTOT] = (_Float16)a1;
    } else {
        const int g = tid & 31, r0 = tid >> 5;  // r0 0..15 -> rows r0, r0+16
        float a0 = 0.0f, a1 = 0.0f;
#pragma unroll
        for (int f = 0; f < FD; ++f) {
            float w = Wg[f * FD + g];
            a0 = __builtin_fmaf(lds_part[f * 32 + r0], w, a0);
            a1 = __builtin_fmaf(lds_part[f * 32 + r0 + 16], w, a1);
        }
        a0 = eluf(a0);
        a1 = eluf(a1);
        float* dst = outF + ((size_t)b * NTOT + rowbase) * FD + g;
        dst[(size_t)r0 * FD] = a0;
        dst[(size_t)(r0 + 16) * FD] = a1;
    }
}

extern "C" void kernel_launch(void* const* d_in, const int* in_sizes, int n_in,
                              void* d_out, int out_size, void* d_ws, size_t ws_size,
                              hipStream_t stream) {
    const float* X = (const float*)d_in[0];  // [B][NT][FD] f32
    const float* W = (const float*)d_in[1];  // [2][FD][FD] f32
    float* out = (float*)d_out;              // [B][NT][FD] f32

    _Float16* Xh = (_Float16*)d_ws;                  // 1 MB
    _Float16* Xht = Xh + (size_t)BATCH * NTOT * FD;  // 1 MB
    _Float16* H1t = Xht + (size_t)BATCH * NTOT * FD; // 1 MB

    convert_x<<<128, 256, 0, stream>>>(X, Xh, Xht);
    gcn_layer_kernel<0><<<BATCH * 128, 512, 0, stream>>>(Xh, Xht, W, H1t, nullptr);
    gcn_layer_kernel<1><<<BATCH * 128, 512, 0, stream>>>(Xh, H1t, W + FD * FD, nullptr, out);
}

// Round 6
// 57.911 us; speedup vs baseline: 2.7565x; 1.5392x over previous
//
#include <hip/hip_runtime.h>

#define NTOT 4096
#define FD 32
#define BATCH 4

typedef __attribute__((ext_vector_type(8))) _Float16 half8;
typedef __attribute__((ext_vector_type(4))) _Float16 half4;
typedef __attribute__((ext_vector_type(2))) _Float16 half2v;
typedef __attribute__((ext_vector_type(4))) float f32x4;

__device__ __forceinline__ float tanh_pos(float t) {
    // tanh(t) for t >= 0:  1 - 2/(1+e^{2t});  t=inf -> 1 correctly
    float u = __builtin_amdgcn_exp2f(t * 2.885390081777927f); // e^{2t}
    float r = __builtin_amdgcn_rcpf(u + 1.0f);
    return __builtin_fmaf(-2.0f, r, 1.0f);
}

__device__ __forceinline__ float eluf(float x) {
    return x > 0.0f ? x : (__builtin_amdgcn_exp2f(x * 1.4426950408889634f) - 1.0f);
}

// X (f32 [B][NT][FD]) -> Kfrag (f16, [B][NT/16 tiles][64 lanes][8]) and
//                        Vfrag (f16, [B][NT/16 tiles][2 fh][64 lanes][4])
// Kfrag[t][l][j]    = X[t*16 + (l&15)][(l>>4)*8 + j]        (B-operand of 16x16x32)
// Vfrag[t][fh][l][j]= X[t*16 + (l>>4)*4 + j][fh*16 + (l&15)] (A-operand of 16x16x16, V^T)
// 128 blocks: xcd = blk&7, batch = xcd>>1, chunk = ((xcd&1)<<4)|(blk>>3) in [0,32).
__global__ __launch_bounds__(256) void convert_x(const float* __restrict__ X,
                                                 _Float16* __restrict__ Kfrag,
                                                 _Float16* __restrict__ Vfrag) {
    __shared__ float lds[128 * 33];
    const int tid = threadIdx.x;
    const int blk = blockIdx.x;            // 128 blocks
    const int xcd = blk & 7;
    const int batch = xcd >> 1;
    const int chunk = ((xcd & 1) << 4) | (blk >> 3);  // 0..31
    const int nbase = chunk << 7;                      // 128 rows per chunk

    const float* Xp = X + ((size_t)batch * NTOT + nbase) * FD;
#pragma unroll
    for (int k = 0; k < 16; ++k) {
        int e = tid + k * 256;
        lds[(e >> 5) * 33 + (e & 31)] = Xp[e];
    }
    __syncthreads();

    // Kfrag: 8 tiles * 512 f16
    {
        _Float16* kout = Kfrag + (size_t)batch * NTOT * FD + (size_t)(nbase >> 4) * 512;
        const int tl = tid >> 5;
        const int l0 = (tid & 31) * 2;
#pragma unroll
        for (int s = 0; s < 2; ++s) {
            int l = l0 + s;
            int row = tl * 16 + (l & 15);
            int cb = (l >> 4) * 8;
            half8 v;
#pragma unroll
            for (int j = 0; j < 8; ++j) v[j] = (_Float16)lds[row * 33 + cb + j];
            *(half8*)(kout + (tl * 64 + l) * 8) = v;
        }
    }
    // Vfrag: 8 tiles * 512 f16
    {
        _Float16* vout = Vfrag + (size_t)batch * NTOT * FD + (size_t)(nbase >> 4) * 512;
        const int tl = tid >> 5;
        const int fh = (tid >> 4) & 1;
        const int lb = (tid & 15) * 4;
#pragma unroll
        for (int li = 0; li < 4; ++li) {
            int lane = lb + li;
            int l15 = lane & 15, lg = lane >> 4;
            half4 v;
#pragma unroll
            for (int j = 0; j < 4; ++j)
                v[j] = (_Float16)lds[(tl * 16 + lg * 4 + j) * 33 + fh * 16 + l15];
            *(half4*)(vout + ((tl * 2 + fh) * 64 + lane) * 4) = v;
        }
    }
}

// One GCN layer: out = elu( adj @ V @ W ), adj = tanh(relu(X X^T) + I)
// 32 rows/block, 8 waves each owning a 512-col strip, 16 iters of 32 cols.
// All loads are fragment-major: base + lane*(16B|8B), fully coalesced.
// LAYER==0: write outHt in Vfrag layout (f16); LAYER==1: write outF (f32 rows).
template <int LAYER>
__global__ __launch_bounds__(512, 4) void gcn_layer_kernel(const _Float16* __restrict__ Kf,
                                                           const _Float16* __restrict__ Vf,
                                                           const float* __restrict__ Wg,
                                                           _Float16* __restrict__ outHt,
                                                           float* __restrict__ outF) {
    __shared__ float lds_part[8 * 32 * 32];  // per-wave partial O^T [wv][f][r], 32 KB

    const int tid = threadIdx.x;
    const int lane = tid & 63;
    const int wv = tid >> 6;            // 8 waves
    const int blk = blockIdx.x;         // 512 blocks
    const int xcd = blk & 7;
    const int b = xcd >> 1;             // batch pinned to XCD pair
    const int rowbase = ((((xcd & 1) << 6) + (blk >> 3))) << 5;  // 128 row-blocks/batch
    const int l15 = lane & 15;
    const int lg = lane >> 4;

    const _Float16* KfB = Kf + (size_t)b * NTOT * FD;
    const _Float16* VfB = Vf + (size_t)b * NTOT * FD;

    // Q fragments (tiles rowbase/16, +1)
    const half8 q1 = *(const half8*)(KfB + (size_t)(rowbase >> 4) * 512 + lane * 8);
    const half8 q2 = *(const half8*)(KfB + (size_t)((rowbase >> 4) + 1) * 512 + lane * 8);

    const int col0 = wv << 9;  // each wave owns 512 columns
    const _Float16* kq = KfB + (size_t)(col0 >> 4) * 512 + lane * 8;
    const _Float16* vq = VfB + (size_t)(col0 >> 4) * 512 + lane * 4;

    f32x4 accA0 = {0.f, 0.f, 0.f, 0.f}, accA1 = {0.f, 0.f, 0.f, 0.f};
    f32x4 accB0 = {0.f, 0.f, 0.f, 0.f}, accB1 = {0.f, 0.f, 0.f, 0.f};
    const f32x4 zero = {0.f, 0.f, 0.f, 0.f};

    // 1-deep software prefetch; all loads contiguous per wave
    half8 k0n = *(const half8*)kq;
    half8 k1n = *(const half8*)(kq + 512);
    half4 v00n = *(const half4*)vq;          // tile0, fh0
    half4 v01n = *(const half4*)(vq + 256);  // tile0, fh1
    half4 v10n = *(const half4*)(vq + 512);  // tile1, fh0
    half4 v11n = *(const half4*)(vq + 768);  // tile1, fh1

    for (int it = 0; it < 16; ++it) {
        const int colbase = col0 + (it << 5);
        half8 k0 = k0n, k1 = k1n;
        half4 v00 = v00n, v01 = v01n, v10 = v10n, v11 = v11n;
        if (it < 15) {  // wave-uniform
            kq += 1024; vq += 1024;
            k0n = *(const half8*)kq;
            k1n = *(const half8*)(kq + 512);
            v00n = *(const half4*)vq;
            v01n = *(const half4*)(vq + 256);
            v10n = *(const half4*)(vq + 512);
            v11n = *(const half4*)(vq + 768);
        }

        // S^T tiles: D[c][r], c = lg*4+e, r = l15
        f32x4 s00 = __builtin_amdgcn_mfma_f32_16x16x32_f16(k0, q1, zero, 0, 0, 0);
        f32x4 s01 = __builtin_amdgcn_mfma_f32_16x16x32_f16(k0, q2, zero, 0, 0, 0);
        f32x4 s10 = __builtin_amdgcn_mfma_f32_16x16x32_f16(k1, q1, zero, 0, 0, 0);
        f32x4 s11 = __builtin_amdgcn_mfma_f32_16x16x32_f16(k1, q2, zero, 0, 0, 0);

        float t00[4], t01[4], t10[4], t11[4];
#pragma unroll
        for (int e = 0; e < 4; ++e) {
            t00[e] = fmaxf(s00[e], 0.0f);
            t01[e] = fmaxf(s01[e], 0.0f);
            t10[e] = fmaxf(s10[e], 0.0f);
            t11[e] = fmaxf(s11[e], 0.0f);
        }
        if (colbase == rowbase) {  // diagonal in (k0,q1) and (k1,q2) at c==r
#pragma unroll
            for (int e = 0; e < 4; ++e)
                if (lg * 4 + e == l15) { t00[e] += 1.0f; t11[e] += 1.0f; }
        }
#pragma unroll
        for (int e = 0; e < 4; ++e) {
            t00[e] = tanh_pos(t00[e]);
            t01[e] = tanh_pos(t01[e]);
            t10[e] = tanh_pos(t10[e]);
            t11[e] = tanh_pos(t11[e]);
        }

        half4 p00 = __builtin_shufflevector(
            __builtin_bit_cast(half2v, __builtin_amdgcn_cvt_pkrtz(t00[0], t00[1])),
            __builtin_bit_cast(half2v, __builtin_amdgcn_cvt_pkrtz(t00[2], t00[3])), 0, 1, 2, 3);
        half4 p01 = __builtin_shufflevector(
            __builtin_bit_cast(half2v, __builtin_amdgcn_cvt_pkrtz(t01[0], t01[1])),
            __builtin_bit_cast(half2v, __builtin_amdgcn_cvt_pkrtz(t01[2], t01[3])), 0, 1, 2, 3);
        half4 p10 = __builtin_shufflevector(
            __builtin_bit_cast(half2v, __builtin_amdgcn_cvt_pkrtz(t10[0], t10[1])),
            __builtin_bit_cast(half2v, __builtin_amdgcn_cvt_pkrtz(t10[2], t10[3])), 0, 1, 2, 3);
        half4 p11 = __builtin_shufflevector(
            __builtin_bit_cast(half2v, __builtin_amdgcn_cvt_pkrtz(t11[0], t11[1])),
            __builtin_bit_cast(half2v, __builtin_amdgcn_cvt_pkrtz(t11[2], t11[3])), 0, 1, 2, 3);

        // O^T += V^T * P^T
        accA0 = __builtin_amdgcn_mfma_f32_16x16x16f16(v00, p00, accA0, 0, 0, 0);
        accA1 = __builtin_amdgcn_mfma_f32_16x16x16f16(v00, p01, accA1, 0, 0, 0);
        accB0 = __builtin_amdgcn_mfma_f32_16x16x16f16(v01, p00, accB0, 0, 0, 0);
        accB1 = __builtin_amdgcn_mfma_f32_16x16x16f16(v01, p01, accB1, 0, 0, 0);
        accA0 = __builtin_amdgcn_mfma_f32_16x16x16f16(v10, p10, accA0, 0, 0, 0);
        accA1 = __builtin_amdgcn_mfma_f32_16x16x16f16(v10, p11, accA1, 0, 0, 0);
        accB0 = __builtin_amdgcn_mfma_f32_16x16x16f16(v11, p10, accB0, 0, 0, 0);
        accB1 = __builtin_amdgcn_mfma_f32_16x16x16f16(v11, p11, accB1, 0, 0, 0);
    }

    // ---- store per-wave partial O^T [f=32][r=32] ----
#pragma unroll
    for (int e = 0; e < 4; ++e) {
        int f0 = lg * 4 + e;
        lds_part[(wv * 32 + f0) * 32 + l15] = accA0[e];
        lds_part[(wv * 32 + f0) * 32 + 16 + l15] = accA1[e];
        lds_part[(wv * 32 + 16 + f0) * 32 + l15] = accB0[e];
        lds_part[(wv * 32 + 16 + f0) * 32 + 16 + l15] = accB1[e];
    }
    __syncthreads();

    // ---- reduce 8 wave partials over 1024 (f,r) slots, 2 per thread ----
#pragma unroll
    for (int k = 0; k < 2; ++k) {
        int o = tid + k * 512;
        float ssum = 0.0f;
#pragma unroll
        for (int ww = 0; ww < 8; ++ww) ssum += lds_part[ww * 1024 + o];
        lds_part[o] = ssum;
    }
    __syncthreads();

    // ---- G = O @ W, elu, write ----
    if (LAYER == 0) {
        // write H1 directly in Vfrag layout (2 f16 per thread)
        const int jp = tid & 1;
        const int vlane = (tid >> 1) & 63;
        const int fh = (tid >> 7) & 1;
        const int tl = tid >> 8;  // 0..1
        const int vl15 = vlane & 15, vlg = vlane >> 4;
        const int g = fh * 16 + vl15;
        const int r0 = tl * 16 + vlg * 4 + jp * 2;
        float a0 = 0.0f, a1 = 0.0f;
#pragma unroll
        for (int f = 0; f < FD; ++f) {
            float w = Wg[f * FD + g];
            a0 = __builtin_fmaf(lds_part[f * 32 + r0], w, a0);
            a1 = __builtin_fmaf(lds_part[f * 32 + r0 + 1], w, a1);
        }
        a0 = eluf(a0);
        a1 = eluf(a1);
        unsigned pk = __builtin_bit_cast(unsigned, __builtin_amdgcn_cvt_pkrtz(a0, a1));
        _Float16* dst = outHt + (size_t)b * NTOT * FD +
                        ((size_t)(((rowbase >> 4) + tl) * 2 + fh) * 64 + vlane) * 4 + jp * 2;
        *(unsigned*)dst = pk;
    } else {
        const int g = tid & 31, r0 = tid >> 5;  // rows r0, r0+16
        float a0 = 0.0f, a1 = 0.0f;
#pragma unroll
        for (int f = 0; f < FD; ++f) {
            float w = Wg[f * FD + g];
            a0 = __builtin_fmaf(lds_part[f * 32 + r0], w, a0);
            a1 = __builtin_fmaf(lds_part[f * 32 + r0 + 16], w, a1);
        }
        a0 = eluf(a0);
        a1 = eluf(a1);
        float* dst = outF + ((size_t)b * NTOT + rowbase) * FD + g;
        dst[(size_t)r0 * FD] = a0;
        dst[(size_t)(r0 + 16) * FD] = a1;
    }
}

extern "C" void kernel_launch(void* const* d_in, const int* in_sizes, int n_in,
                              void* d_out, int out_size, void* d_ws, size_t ws_size,
                              hipStream_t stream) {
    const float* X = (const float*)d_in[0];  // [B][NT][FD] f32
    const float* W = (const float*)d_in[1];  // [2][FD][FD] f32
    float* out = (float*)d_out;              // [B][NT][FD] f32

    _Float16* Kfrag = (_Float16*)d_ws;                    // 1 MB
    _Float16* VfragX = Kfrag + (size_t)BATCH * NTOT * FD; // 1 MB
    _Float16* H1frag = VfragX + (size_t)BATCH * NTOT * FD;// 1 MB

    convert_x<<<128, 256, 0, stream>>>(X, Kfrag, VfragX);
    gcn_layer_kernel<0><<<512, 512, 0, stream>>>(Kfrag, VfragX, W, H1frag, nullptr);
    gcn_layer_kernel<1><<<512, 512, 0, stream>>>(Kfrag, H1frag, W + FD * FD, nullptr, out);
}

// Round 7
// 51.850 us; speedup vs baseline: 3.0788x; 1.1169x over previous
//
#include <hip/hip_runtime.h>

#define NTOT 4096
#define FD 32
#define BATCH 4

typedef __attribute__((ext_vector_type(8))) _Float16 half8;
typedef __attribute__((ext_vector_type(4))) _Float16 half4;
typedef __attribute__((ext_vector_type(2))) _Float16 half2v;
typedef __attribute__((ext_vector_type(4))) float f32x4;

__device__ __forceinline__ float tanh_pos(float t) {
    // tanh(t) for t >= 0:  1 - 2/(1+e^{2t});  t=inf -> 1 correctly
    float u = __builtin_amdgcn_exp2f(t * 2.885390081777927f); // e^{2t}
    float r = __builtin_amdgcn_rcpf(u + 1.0f);
    return __builtin_fmaf(-2.0f, r, 1.0f);
}

__device__ __forceinline__ float tanh_poly(float t) {
    // tanh(t) ~= t*(1 - t^2/3 + 2 t^4/15), |err| < 3e-6 for t in [0, 0.25]
    float t2 = t * t;
    float c = __builtin_fmaf(t2, 0.1333333333f, -0.3333333333f);
    return __builtin_fmaf(t * t2, c, t);
}

__device__ __forceinline__ float eluf(float x) {
    return x > 0.0f ? x : (__builtin_amdgcn_exp2f(x * 1.4426950408889634f) - 1.0f);
}

// X (f32 [B][NT][FD]) -> Kfrag (f16, [B][NT/16 tiles][64 lanes][8]) and
//                        Vfrag (f16, [B][NT/16 tiles][2 fh][64 lanes][4])
// Kfrag[t][l][j]    = X[t*16 + (l&15)][(l>>4)*8 + j]        (B-operand of 16x16x32)
// Vfrag[t][fh][l][j]= X[t*16 + (l>>4)*4 + j][fh*16 + (l&15)] (A-operand of 16x16x16, V^T)
// 128 blocks: xcd = blk&7, batch = xcd>>1, chunk = ((xcd&1)<<4)|(blk>>3) in [0,32).
__global__ __launch_bounds__(256) void convert_x(const float* __restrict__ X,
                                                 _Float16* __restrict__ Kfrag,
                                                 _Float16* __restrict__ Vfrag) {
    __shared__ float lds[128 * 33];
    const int tid = threadIdx.x;
    const int blk = blockIdx.x;            // 128 blocks
    const int xcd = blk & 7;
    const int batch = xcd >> 1;
    const int chunk = ((xcd & 1) << 4) | (blk >> 3);  // 0..31
    const int nbase = chunk << 7;                      // 128 rows per chunk

    const float* Xp = X + ((size_t)batch * NTOT + nbase) * FD;
#pragma unroll
    for (int k = 0; k < 16; ++k) {
        int e = tid + k * 256;
        lds[(e >> 5) * 33 + (e & 31)] = Xp[e];
    }
    __syncthreads();

    // Kfrag: 8 tiles * 512 f16
    {
        _Float16* kout = Kfrag + (size_t)batch * NTOT * FD + (size_t)(nbase >> 4) * 512;
        const int tl = tid >> 5;
        const int l0 = (tid & 31) * 2;
#pragma unroll
        for (int s = 0; s < 2; ++s) {
            int l = l0 + s;
            int row = tl * 16 + (l & 15);
            int cb = (l >> 4) * 8;
            half8 v;
#pragma unroll
            for (int j = 0; j < 8; ++j) v[j] = (_Float16)lds[row * 33 + cb + j];
            *(half8*)(kout + (tl * 64 + l) * 8) = v;
        }
    }
    // Vfrag: 8 tiles * 512 f16
    {
        _Float16* vout = Vfrag + (size_t)batch * NTOT * FD + (size_t)(nbase >> 4) * 512;
        const int tl = tid >> 5;
        const int fh = (tid >> 4) & 1;
        const int lb = (tid & 15) * 4;
#pragma unroll
        for (int li = 0; li < 4; ++li) {
            int lane = lb + li;
            int l15 = lane & 15, lg = lane >> 4;
            half4 v;
#pragma unroll
            for (int j = 0; j < 4; ++j)
                v[j] = (_Float16)lds[(tl * 16 + lg * 4 + j) * 33 + fh * 16 + l15];
            *(half4*)(vout + ((tl * 2 + fh) * 64 + lane) * 4) = v;
        }
    }
}

// One GCN layer: out = elu( adj @ V @ W ), adj = tanh(relu(X X^T) + I)
// 32 rows/block, 8 waves each owning a 512-col strip, 16 iters of 32 cols.
// tanh via wave-uniform ballot: tiles with all scores <= 0.25 (99%+) use a
// 4-op polynomial (no transcendentals); others (diagonal) use exact tanh.
// LAYER==0: write outHt in Vfrag layout (f16); LAYER==1: write outF (f32 rows).
template <int LAYER>
__global__ __launch_bounds__(512, 4) void gcn_layer_kernel(const _Float16* __restrict__ Kf,
                                                           const _Float16* __restrict__ Vf,
                                                           const float* __restrict__ Wg,
                                                           _Float16* __restrict__ outHt,
                                                           float* __restrict__ outF) {
    __shared__ float lds_part[8 * 32 * 32];  // per-wave partial O^T [wv][f][r], 32 KB

    const int tid = threadIdx.x;
    const int lane = tid & 63;
    const int wv = tid >> 6;            // 8 waves
    const int blk = blockIdx.x;         // 512 blocks
    const int xcd = blk & 7;
    const int b = xcd >> 1;             // batch pinned to XCD pair
    const int rowbase = ((((xcd & 1) << 6) + (blk >> 3))) << 5;  // 128 row-blocks/batch
    const int l15 = lane & 15;
    const int lg = lane >> 4;

    const _Float16* KfB = Kf + (size_t)b * NTOT * FD;
    const _Float16* VfB = Vf + (size_t)b * NTOT * FD;

    // Q fragments (tiles rowbase/16, +1)
    const half8 q1 = *(const half8*)(KfB + (size_t)(rowbase >> 4) * 512 + lane * 8);
    const half8 q2 = *(const half8*)(KfB + (size_t)((rowbase >> 4) + 1) * 512 + lane * 8);

    const int col0 = wv << 9;  // each wave owns 512 columns
    const _Float16* kq = KfB + (size_t)(col0 >> 4) * 512 + lane * 8;
    const _Float16* vq = VfB + (size_t)(col0 >> 4) * 512 + lane * 4;

    f32x4 accA0 = {0.f, 0.f, 0.f, 0.f}, accA1 = {0.f, 0.f, 0.f, 0.f};
    f32x4 accB0 = {0.f, 0.f, 0.f, 0.f}, accB1 = {0.f, 0.f, 0.f, 0.f};
    const f32x4 zero = {0.f, 0.f, 0.f, 0.f};

    // 1-deep software prefetch; all loads contiguous per wave
    half8 k0n = *(const half8*)kq;
    half8 k1n = *(const half8*)(kq + 512);
    half4 v00n = *(const half4*)vq;          // tile0, fh0
    half4 v01n = *(const half4*)(vq + 256);  // tile0, fh1
    half4 v10n = *(const half4*)(vq + 512);  // tile1, fh0
    half4 v11n = *(const half4*)(vq + 768);  // tile1, fh1

    for (int it = 0; it < 16; ++it) {
        const int colbase = col0 + (it << 5);
        half8 k0 = k0n, k1 = k1n;
        half4 v00 = v00n, v01 = v01n, v10 = v10n, v11 = v11n;
        if (it < 15) {  // wave-uniform
            kq += 1024; vq += 1024;
            k0n = *(const half8*)kq;
            k1n = *(const half8*)(kq + 512);
            v00n = *(const half4*)vq;
            v01n = *(const half4*)(vq + 256);
            v10n = *(const half4*)(vq + 512);
            v11n = *(const half4*)(vq + 768);
        }

        // S^T tiles: D[c][r], c = lg*4+e, r = l15
        f32x4 s00 = __builtin_amdgcn_mfma_f32_16x16x32_f16(k0, q1, zero, 0, 0, 0);
        f32x4 s01 = __builtin_amdgcn_mfma_f32_16x16x32_f16(k0, q2, zero, 0, 0, 0);
        f32x4 s10 = __builtin_amdgcn_mfma_f32_16x16x32_f16(k1, q1, zero, 0, 0, 0);
        f32x4 s11 = __builtin_amdgcn_mfma_f32_16x16x32_f16(k1, q2, zero, 0, 0, 0);

        float t00[4], t01[4], t10[4], t11[4];
#pragma unroll
        for (int e = 0; e < 4; ++e) {
            t00[e] = fmaxf(s00[e], 0.0f);
            t01[e] = fmaxf(s01[e], 0.0f);
            t10[e] = fmaxf(s10[e], 0.0f);
            t11[e] = fmaxf(s11[e], 0.0f);
        }
        if (colbase == rowbase) {  // diagonal in (k0,q1) and (k1,q2) at c==r
#pragma unroll
            for (int e = 0; e < 4; ++e)
                if (lg * 4 + e == l15) { t00[e] += 1.0f; t11[e] += 1.0f; }
        }

        // wave-uniform fast/slow select on the max of this lane's 16 scores
        float m = 0.0f;
#pragma unroll
        for (int e = 0; e < 4; ++e) {
            m = fmaxf(m, fmaxf(fmaxf(t00[e], t01[e]), fmaxf(t10[e], t11[e])));
        }
        if (__any(m > 0.25f)) {
#pragma unroll
            for (int e = 0; e < 4; ++e) {
                t00[e] = tanh_pos(t00[e]);
                t01[e] = tanh_pos(t01[e]);
                t10[e] = tanh_pos(t10[e]);
                t11[e] = tanh_pos(t11[e]);
            }
        } else {
#pragma unroll
            for (int e = 0; e < 4; ++e) {
                t00[e] = tanh_poly(t00[e]);
                t01[e] = tanh_poly(t01[e]);
                t10[e] = tanh_poly(t10[e]);
                t11[e] = tanh_poly(t11[e]);
            }
        }

        half4 p00 = __builtin_shufflevector(
            __builtin_bit_cast(half2v, __builtin_amdgcn_cvt_pkrtz(t00[0], t00[1])),
            __builtin_bit_cast(half2v, __builtin_amdgcn_cvt_pkrtz(t00[2], t00[3])), 0, 1, 2, 3);
        half4 p01 = __builtin_shufflevector(
            __builtin_bit_cast(half2v, __builtin_amdgcn_cvt_pkrtz(t01[0], t01[1])),
            __builtin_bit_cast(half2v, __builtin_amdgcn_cvt_pkrtz(t01[2], t01[3])), 0, 1, 2, 3);
        half4 p10 = __builtin_shufflevector(
            __builtin_bit_cast(half2v, __builtin_amdgcn_cvt_pkrtz(t10[0], t10[1])),
            __builtin_bit_cast(half2v, __builtin_amdgcn_cvt_pkrtz(t10[2], t10[3])), 0, 1, 2, 3);
        half4 p11 = __builtin_shufflevector(
            __builtin_bit_cast(half2v, __builtin_amdgcn_cvt_pkrtz(t11[0], t11[1])),
            __builtin_bit_cast(half2v, __builtin_amdgcn_cvt_pkrtz(t11[2], t11[3])), 0, 1, 2, 3);

        // O^T += V^T * P^T
        accA0 = __builtin_amdgcn_mfma_f32_16x16x16f16(v00, p00, accA0, 0, 0, 0);
        accA1 = __builtin_amdgcn_mfma_f32_16x16x16f16(v00, p01, accA1, 0, 0, 0);
        accB0 = __builtin_amdgcn_mfma_f32_16x16x16f16(v01, p00, accB0, 0, 0, 0);
        accB1 = __builtin_amdgcn_mfma_f32_16x16x16f16(v01, p01, accB1, 0, 0, 0);
        accA0 = __builtin_amdgcn_mfma_f32_16x16x16f16(v10, p10, accA0, 0, 0, 0);
        accA1 = __builtin_amdgcn_mfma_f32_16x16x16f16(v10, p11, accA1, 0, 0, 0);
        accB0 = __builtin_amdgcn_mfma_f32_16x16x16f16(v11, p10, accB0, 0, 0, 0);
        accB1 = __builtin_amdgcn_mfma_f32_16x16x16f16(v11, p11, accB1, 0, 0, 0);
    }

    // ---- store per-wave partial O^T [f=32][r=32] ----
#pragma unroll
    for (int e = 0; e < 4; ++e) {
        int f0 = lg * 4 + e;
        lds_part[(wv * 32 + f0) * 32 + l15] = accA0[e];
        lds_part[(wv * 32 + f0) * 32 + 16 + l15] = accA1[e];
        lds_part[(wv * 32 + 16 + f0) * 32 + l15] = accB0[e];
        lds_part[(wv * 32 + 16 + f0) * 32 + 16 + l15] = accB1[e];
    }
    __syncthreads();

    // ---- reduce 8 wave partials over 1024 (f,r) slots, 2 per thread ----
#pragma unroll
    for (int k = 0; k < 2; ++k) {
        int o = tid + k * 512;
        float ssum = 0.0f;
#pragma unroll
        for (int ww = 0; ww < 8; ++ww) ssum += lds_part[ww * 1024 + o];
        lds_part[o] = ssum;
    }
    __syncthreads();

    // ---- G = O @ W, elu, write ----
    if (LAYER == 0) {
        // write H1 directly in Vfrag layout (2 f16 per thread)
        const int jp = tid & 1;
        const int vlane = (tid >> 1) & 63;
        const int fh = (tid >> 7) & 1;
        const int tl = tid >> 8;  // 0..1
        const int vl15 = vlane & 15, vlg = vlane >> 4;
        const int g = fh * 16 + vl15;
        const int r0 = tl * 16 + vlg * 4 + jp * 2;
        float a0 = 0.0f, a1 = 0.0f;
#pragma unroll
        for (int f = 0; f < FD; ++f) {
            float w = Wg[f * FD + g];
            a0 = __builtin_fmaf(lds_part[f * 32 + r0], w, a0);
            a1 = __builtin_fmaf(lds_part[f * 32 + r0 + 1], w, a1);
        }
        a0 = eluf(a0);
        a1 = eluf(a1);
        unsigned pk = __builtin_bit_cast(unsigned, __builtin_amdgcn_cvt_pkrtz(a0, a1));
        _Float16* dst = outHt + (size_t)b * NTOT * FD +
                        ((size_t)(((rowbase >> 4) + tl) * 2 + fh) * 64 + vlane) * 4 + jp * 2;
        *(unsigned*)dst = pk;
    } else {
        const int g = tid & 31, r0 = tid >> 5;  // rows r0, r0+16
        float a0 = 0.0f, a1 = 0.0f;
#pragma unroll
        for (int f = 0; f < FD; ++f) {
            float w = Wg[f * FD + g];
            a0 = __builtin_fmaf(lds_part[f * 32 + r0], w, a0);
            a1 = __builtin_fmaf(lds_part[f * 32 + r0 + 16], w, a1);
        }
        a0 = eluf(a0);
        a1 = eluf(a1);
        float* dst = outF + ((size_t)b * NTOT + rowbase) * FD + g;
        dst[(size_t)r0 * FD] = a0;
        dst[(size_t)(r0 + 16) * FD] = a1;
    }
}

extern "C" void kernel_launch(void* const* d_in, const int* in_sizes, int n_in,
                              void* d_out, int out_size, void* d_ws, size_t ws_size,
                              hipStream_t stream) {
    const float* X = (const float*)d_in[0];  // [B][NT][FD] f32
    const float* W = (const float*)d_in[1];  // [2][FD][FD] f32
    float* out = (float*)d_out;              // [B][NT][FD] f32

    _Float16* Kfrag = (_Float16*)d_ws;                    // 1 MB
    _Float16* VfragX = Kfrag + (size_t)BATCH * NTOT * FD; // 1 MB
    _Float16* H1frag = VfragX + (size_t)BATCH * NTOT * FD;// 1 MB

    convert_x<<<128, 256, 0, stream>>>(X, Kfrag, VfragX);
    gcn_layer_kernel<0><<<512, 512, 0, stream>>>(Kfrag, VfragX, W, H1frag, nullptr);
    gcn_layer_kernel<1><<<512, 512, 0, stream>>>(Kfrag, H1frag, W + FD * FD, nullptr, out);
}